// Round 1
// baseline (2081.305 us; speedup 1.0000x reference)
//
#include <hip/hip_runtime.h>

#define TPB 256

// ---------------------------------------------------------------------------
// Fused VIGNet forward: per-block = one batch element.
// LDS ping-pong:  bufB holds x (stage1 in) then h2; bufA holds h1 then h3.
// wbuf holds the current stage's weights (<= 1010 floats).
//
// Stage weight layout inside wbuf:
//   [0..500)   conv kernel   ck[(w*CIN+cin)*10 + c]
//   [500..510) conv bias     cb[c]
//   [510..520) bn scale      g*rsqrt(v+eps)
//   [520..530) bn shift      be - m*scale
//   [530..930) attn K        aK[((i*2+h)*CIN+cin)*2 + o]
//   [930..950) attn bias     ab[i*2+o]
//   [950..1000) attn dw      adw[w*10+i]
//   [1000..1010) attn db     adb[i]
// ---------------------------------------------------------------------------

__device__ __forceinline__ void load_stage_w(
    float* w,
    const float* ck, int ckn, const float* cb,
    const float* g, const float* be, const float* m, const float* v,
    const float* aK, int aKn, const float* ab,
    const float* adw, const float* adb)
{
  const int tid = threadIdx.x;
  for (int i = tid; i < ckn; i += TPB) w[i] = ck[i];
  if (tid < 10) w[500 + tid] = cb[tid];
  if (tid < 10) {
    float sc = g[tid] * rsqrtf(v[tid] + 1e-3f);
    w[510 + tid] = sc;
    w[520 + tid] = be[tid] - m[tid] * sc;
  }
  for (int i = tid; i < aKn; i += TPB) w[530 + i] = aK[i];
  if (tid < 20) w[930 + tid] = ab[tid];
  if (tid < 50) w[950 + tid] = adw[tid];
  if (tid < 10) w[1000 + tid] = adb[tid];
}

// One fused stage: h_out[c][o][t] = lrelu(bn(conv5(h_in))) * softmax_i(mhrssa)
// in  layout: in[(cin*2 + h)*Tin + t]
// out layout: out[(c*2 + o)*Tout + t]
template <int CIN>
__device__ __forceinline__ void run_stage(
    const float* in, float* out, int Tin, int Tout, const float* w)
{
  const float* ck    = w;
  const float* cb    = w + 500;
  const float* scale = w + 510;
  const float* shift = w + 520;
  const float* aK    = w + 530;
  const float* ab    = w + 930;
  const float* adw   = w + 950;
  const float* adb   = w + 1000;

  const int tid = threadIdx.x;
  const int o   = tid >> 7;        // 0..1
  const int ln  = tid & 127;       // 0..127
  const int t0  = ln * 8;
  if (t0 >= Tout) return;          // no syncs below -> safe early-out

  // m[i] at time tt (the mhrssa einsum output, pre-depthwise)
  float ring[5][10];
  auto mcalc = [&](int tt, float* dst) {
    float xv[2][CIN];
#pragma unroll
    for (int h = 0; h < 2; ++h)
#pragma unroll
      for (int ci = 0; ci < CIN; ++ci)
        xv[h][ci] = in[(ci * 2 + h) * Tin + tt];
#pragma unroll
    for (int i = 0; i < 10; ++i) {
      float acc = ab[i * 2 + o];
#pragma unroll
      for (int h = 0; h < 2; ++h)
#pragma unroll
        for (int ci = 0; ci < CIN; ++ci)
          acc += xv[h][ci] * aK[((i * 2 + h) * CIN + ci) * 2 + o];
      dst[i] = acc;
    }
  };

#pragma unroll
  for (int k = 0; k < 4; ++k) mcalc(t0 + k, ring[k]);

#pragma unroll 1
  for (int s = 0; s < 8; ++s) {
    const int t = t0 + s;
    if (t >= Tout) break;
    mcalc(t + 4, ring[4]);

    // depthwise (1,5) over the ring -> pre-softmax logits y[i]
    float y[10];
#pragma unroll
    for (int i = 0; i < 10; ++i) {
      float acc = adb[i];
#pragma unroll
      for (int wk = 0; wk < 5; ++wk)
        acc += ring[wk][i] * adw[wk * 10 + i];
      y[i] = acc;
    }

    // conv (1,5) valid, CIN -> 10
    float cv[10];
#pragma unroll
    for (int c = 0; c < 10; ++c) cv[c] = cb[c];
#pragma unroll
    for (int wk = 0; wk < 5; ++wk)
#pragma unroll
      for (int ci = 0; ci < CIN; ++ci) {
        const float xin = in[(ci * 2 + o) * Tin + t + wk];
#pragma unroll
        for (int c = 0; c < 10; ++c)
          cv[c] += xin * ck[(wk * CIN + ci) * 10 + c];
      }

    // softmax over the 10 heads
    float mx = y[0];
#pragma unroll
    for (int i = 1; i < 10; ++i) mx = fmaxf(mx, y[i]);
    float e[10], sm = 0.f;
#pragma unroll
    for (int i = 0; i < 10; ++i) { e[i] = __expf(y[i] - mx); sm += e[i]; }
    const float inv = 1.0f / sm;

    // bn + leaky-relu + attention multiply + store
#pragma unroll
    for (int c = 0; c < 10; ++c) {
      float bnv = cv[c] * scale[c] + shift[c];
      bnv = (bnv >= 0.f) ? bnv : 0.2f * bnv;
      out[(c * 2 + o) * Tout + t] = bnv * e[c] * inv;
    }

    // slide the ring
#pragma unroll
    for (int wk = 0; wk < 4; ++wk)
#pragma unroll
      for (int i = 0; i < 10; ++i)
        ring[wk][i] = ring[wk + 1][i];
  }
}

__global__ __launch_bounds__(TPB, 1) void vignet_kernel(
    const float* __restrict__ x,
    const float* __restrict__ c1k, const float* __restrict__ c1b,
    const float* __restrict__ c2k, const float* __restrict__ c2b,
    const float* __restrict__ c3k, const float* __restrict__ c3b,
    const float* __restrict__ c4k, const float* __restrict__ c4b,
    const float* __restrict__ g1, const float* __restrict__ be1,
    const float* __restrict__ m1, const float* __restrict__ v1,
    const float* __restrict__ g2, const float* __restrict__ be2,
    const float* __restrict__ m2, const float* __restrict__ v2,
    const float* __restrict__ g3, const float* __restrict__ be3,
    const float* __restrict__ m3, const float* __restrict__ v3,
    const float* __restrict__ dnsw, const float* __restrict__ dnsb,
    const float* __restrict__ a1K, const float* __restrict__ a1b,
    const float* __restrict__ a1dw, const float* __restrict__ a1db,
    const float* __restrict__ a2K, const float* __restrict__ a2b,
    const float* __restrict__ a2dw, const float* __restrict__ a2db,
    const float* __restrict__ a3K, const float* __restrict__ a3b,
    const float* __restrict__ a3dw, const float* __restrict__ a3db,
    float* __restrict__ out)
{
  __shared__ float bufA[2 * 996 * 10];   // h1 then h3
  __shared__ float bufB[2 * 992 * 10];   // x then h2
  __shared__ float wbuf[1024];
  __shared__ float red[8];

  const int b   = blockIdx.x;
  const int tid = threadIdx.x;

  // x[b] -> bufB as [h][t]  (== generic layout with CIN=1)
  for (int i = tid; i < 2000; i += TPB) bufB[i] = x[b * 2000 + i];
  load_stage_w(wbuf, c1k, 50, c1b, g1, be1, m1, v1, a1K, 40, a1b, a1dw, a1db);
  __syncthreads();

  run_stage<1>(bufB, bufA, 1000, 996, wbuf);        // h1 -> bufA
  __syncthreads();
  load_stage_w(wbuf, c2k, 500, c2b, g2, be2, m2, v2, a2K, 400, a2b, a2dw, a2db);
  __syncthreads();

  run_stage<10>(bufA, bufB, 996, 992, wbuf);        // h2 -> bufB
  __syncthreads();
  load_stage_w(wbuf, c3k, 500, c3b, g3, be3, m3, v3, a3K, 400, a3b, a3dw, a3db);
  __syncthreads();

  run_stage<10>(bufB, bufA, 992, 988, wbuf);        // h3 -> bufA
  __syncthreads();

  // stage4 weights: c4k[(h*10+cin)*20+cc] at [0..400), c4b at [400..420)
  for (int i = tid; i < 400; i += TPB) wbuf[i] = c4k[i];
  if (tid < 20) wbuf[400 + tid] = c4b[tid];
  __syncthreads();

  // conv4 (2,1) -> lrelu -> dot with dns_w, reduced across the block
  float partial = 0.f;
  for (int tt = tid; tt < 988; tt += TPB) {
    float xv[2][10];
#pragma unroll
    for (int h = 0; h < 2; ++h)
#pragma unroll
      for (int ci = 0; ci < 10; ++ci)
        xv[h][ci] = bufA[(ci * 2 + h) * 988 + tt];
    const float* dwp = dnsw + tt * 20;
    float dot = 0.f;
#pragma unroll
    for (int cc = 0; cc < 20; ++cc) {
      float acc = wbuf[400 + cc];
#pragma unroll
      for (int h = 0; h < 2; ++h)
#pragma unroll
        for (int ci = 0; ci < 10; ++ci)
          acc += xv[h][ci] * wbuf[(h * 10 + ci) * 20 + cc];
      acc = (acc >= 0.f) ? acc : 0.2f * acc;
      dot += acc * dwp[cc];
    }
    partial += dot;
  }

#pragma unroll
  for (int off = 32; off > 0; off >>= 1)
    partial += __shfl_down(partial, off, 64);
  if ((tid & 63) == 0) red[tid >> 6] = partial;
  __syncthreads();
  if (tid == 0)
    out[b] = red[0] + red[1] + red[2] + red[3] + dnsb[0];
}

extern "C" void kernel_launch(void* const* d_in, const int* in_sizes, int n_in,
                              void* d_out, int out_size, void* d_ws, size_t ws_size,
                              hipStream_t stream) {
  const float* p[35];
  for (int i = 0; i < 35; ++i) p[i] = (const float*)d_in[i];
  const int B = in_sizes[0] / 2000;

  vignet_kernel<<<dim3(B), dim3(TPB), 0, stream>>>(
      p[0],                       // x
      p[1], p[2],                 // c1k c1b
      p[3], p[4],                 // c2k c2b
      p[5], p[6],                 // c3k c3b
      p[7], p[8],                 // c4k c4b
      p[9], p[10], p[11], p[12],  // bn1
      p[13], p[14], p[15], p[16], // bn2
      p[17], p[18], p[19], p[20], // bn3
      p[21], p[22],               // dns_w dns_b
      p[23], p[24], p[25], p[26], // a1
      p[27], p[28], p[29], p[30], // a2
      p[31], p[32], p[33], p[34], // a3
      (float*)d_out);
}